// Round 8
// baseline (88.777 us; speedup 1.0000x reference)
//
#include <hip/hip_runtime.h>
#include <hip/hip_bf16.h>

#define NPIX 65536
#define NRAYS 65536
#define SS 48
#define NC 256
#define ND 16
#define RPB 128   // rays per kDist block (128 threads)

typedef __attribute__((ext_vector_type(4))) float f32x4v;

// ---------------- kA: pixel pass (rgb, opac, class count/sum, norm) ----------------
__global__ __launch_bounds__(256) void kA(
    const float* __restrict__ rgb_pred, const float* __restrict__ rgb_gt,
    const float* __restrict__ opacity, const int* __restrict__ sam,
    const float* __restrict__ semantic,
    float* __restrict__ o_rgb, float* __restrict__ o_opac,
    float* __restrict__ cntpart, float* __restrict__ usumpart,
    float* __restrict__ scal, int ppbA)
{
    __shared__ float cnt_s[NC];
    __shared__ float us_s[NC*17];      // stride 17: breaks 2-bank scatter pathology
    __shared__ float red_s[8];
    const int t = threadIdx.x;
    const int b = blockIdx.x;
    for (int j = t; j < NC; j += 256) cnt_s[j] = 0.f;
    for (int j = t; j < NC*17; j += 256) us_s[j] = 0.f;
    __syncthreads();
    float nloc = 0.f, wloc = 0.f;
    for (int p = 0; p < ppbA; ++p) {
        const int i = (b*ppbA + p)*256 + t;
        const float pr0 = rgb_pred[3*i+0], pr1 = rgb_pred[3*i+1], pr2 = rgb_pred[3*i+2];
        const float g0 = rgb_gt[3*i+0],  g1 = rgb_gt[3*i+1],  g2 = rgb_gt[3*i+2];
        const float d0 = pr0-g0, d1 = pr1-g1, d2 = pr2-g2;
        o_rgb[3*i+0] = d0*d0; o_rgb[3*i+1] = d1*d1; o_rgb[3*i+2] = d2*d2;
        const float o = opacity[i] + 1e-10f;
        o_opac[i] = -0.001f * o * logf(o);
        const float4* sp = (const float4*)(semantic + (size_t)i*ND);
        const float4 a0 = sp[0], a1 = sp[1], a2 = sp[2], a3 = sp[3];
        const int seg = sam[i];
        if (seg > 0) {
            const int cl = seg - 1;
            const float ss =
                a0.x*a0.x + a0.y*a0.y + a0.z*a0.z + a0.w*a0.w +
                a1.x*a1.x + a1.y*a1.y + a1.z*a1.z + a1.w*a1.w +
                a2.x*a2.x + a2.y*a2.y + a2.z*a2.z + a2.w*a2.w +
                a3.x*a3.x + a3.y*a3.y + a3.z*a3.z + a3.w*a3.w;
            const float dn = sqrtf(ss) - 1.f;
            nloc += dn*dn; wloc += 1.f;
            atomicAdd(&cnt_s[cl], 1.f);
            float* up = us_s + cl*17;
            atomicAdd(up+0,  a0.x); atomicAdd(up+1,  a0.y);
            atomicAdd(up+2,  a0.z); atomicAdd(up+3,  a0.w);
            atomicAdd(up+4,  a1.x); atomicAdd(up+5,  a1.y);
            atomicAdd(up+6,  a1.z); atomicAdd(up+7,  a1.w);
            atomicAdd(up+8,  a2.x); atomicAdd(up+9,  a2.y);
            atomicAdd(up+10, a2.z); atomicAdd(up+11, a2.w);
            atomicAdd(up+12, a3.x); atomicAdd(up+13, a3.y);
            atomicAdd(up+14, a3.z); atomicAdd(up+15, a3.w);
        }
    }
    __syncthreads();
    for (int j = t; j < NC; j += 256) cntpart[b*NC + j] = cnt_s[j];
    for (int j = t; j < NC*ND; j += 256) {
        const int c = j >> 4, k = j & 15;
        usumpart[(size_t)b*NC*ND + j] = us_s[c*17 + k];
    }
    for (int off = 32; off > 0; off >>= 1) {
        nloc += __shfl_down(nloc, off);
        wloc += __shfl_down(wloc, off);
    }
    if ((t & 63) == 0) { red_s[t>>6] = nloc; red_s[4 + (t>>6)] = wloc; }
    __syncthreads();
    if (t == 0) {
        atomicAdd(&scal[0], red_s[0]+red_s[1]+red_s[2]+red_s[3]);
        atomicAdd(&scal[1], red_s[4]+red_s[5]+red_s[6]+red_s[7]);
    }
}

// ---------------- kDist: LDS-transposed serial scan, 1 thread/ray ----------------
__global__ __launch_bounds__(128) void kDist(
    const float* __restrict__ wsv, const float* __restrict__ deltas,
    const float* __restrict__ tsv, const int* __restrict__ rays_a,
    float* __restrict__ o_dist)
{
    __shared__ float wS[SS][RPB+1];
    __shared__ float tS[SS][RPB+1];
    __shared__ float dS[SS][RPB+1];
    __shared__ int bad;
    const int t = threadIdx.x;
    const int r0 = blockIdx.x * RPB;
    const int ray = r0 + t;
    if (t == 0) bad = 0;
    __syncthreads();
    const int start = rays_a[3*ray + 1];
    const int cnt   = rays_a[3*ray + 2];
    if (start != ray*SS || cnt != SS) atomicAdd(&bad, 1);
    __syncthreads();

    if (bad == 0) {
        const size_t gb = (size_t)r0 * SS;
        const float4* gw = (const float4*)(wsv + gb);
        const float4* gt = (const float4*)(tsv + gb);
        const float4* gd = (const float4*)(deltas + gb);
        for (int i = t; i < RPB*SS/4; i += 128) {
            const int e = i*4;
            const int rr = e / SS;
            const int jj = e % SS;       // multiple of 4, never crosses a ray
            const float4 a = gw[i], b = gt[i], c = gd[i];
            wS[jj+0][rr]=a.x; wS[jj+1][rr]=a.y; wS[jj+2][rr]=a.z; wS[jj+3][rr]=a.w;
            tS[jj+0][rr]=b.x; tS[jj+1][rr]=b.y; tS[jj+2][rr]=b.z; tS[jj+3][rr]=b.w;
            dS[jj+0][rr]=c.x; dS[jj+1][rr]=c.y; dS[jj+2][rr]=c.z; dS[jj+3][rr]=c.w;
        }
        __syncthreads();
        float W = 0.f, WT = 0.f, acc = 0.f;
        for (int j = 0; j < SS; ++j) {
            const float w_ = wS[j][t], t_ = tS[j][t], d_ = dS[j][t];
            acc += 2.f*w_*(t_*W - WT) + w_*w_*d_*(1.f/3.f);
            W += w_; WT += w_*t_;
        }
        o_dist[ray] = 0.001f * acc;
    } else {
        float W = 0.f, WT = 0.f, acc = 0.f;
        for (int j = 0; j < cnt; ++j) {
            const float w_ = wsv[start+j], t_ = tsv[start+j], d_ = deltas[start+j];
            acc += 2.f*w_*(t_*W - WT) + w_*w_*d_*(1.f/3.f);
            W += w_; WT += w_*t_;
        }
        o_dist[ray] = 0.001f * acc;
    }
}

// ---------------- kP1: per-class block reduce -> cnt, u ----------------
__global__ __launch_bounds__(256) void kP1(
    const float* __restrict__ cntpart, const float* __restrict__ usumpart,
    float* __restrict__ cnt, float* __restrict__ u, int nblkA)
{
    const int c = blockIdx.x;
    const int t = threadIdx.x;
    const int kk = t & 15;
    const int s  = t >> 4;

    float us = 0.f;
    for (int b = s; b < nblkA; b += 16)
        us += usumpart[(size_t)b*(NC*ND) + c*ND + kk];

    __shared__ float lds[16][17];
    lds[s][kk] = us;

    float cs = (t < nblkA) ? cntpart[t*NC + c] : 0.f;
#pragma unroll
    for (int off = 32; off > 0; off >>= 1) cs += __shfl_xor(cs, off);
    __shared__ float cred[4];
    if ((t & 63) == 0) cred[t >> 6] = cs;
    __syncthreads();

    if (t < 16) {
        const float ctot = cred[0]+cred[1]+cred[2]+cred[3];
        float tot = 0.f;
#pragma unroll
        for (int s2 = 0; s2 < 16; ++s2) tot += lds[s2][t];
        u[c*ND + t] = tot / fmaxf(ctot, 1.f);
        if (t == 0) cnt[c] = ctot;
    }
}

// ---------------- kC: per-class deviation partials ----------------
__global__ __launch_bounds__(256) void kC(
    const float* __restrict__ semantic, const int* __restrict__ sam,
    const float* __restrict__ u, float* __restrict__ devpart, int ppb)
{
    __shared__ float u_s[NC*20];   // stride 20: float4-aligned, spreads banks
    __shared__ float dev_s[NC];
    const int t = threadIdx.x, b = blockIdx.x;
    for (int j = t; j < NC*ND; j += 256) {
        const int c = j >> 4, k = j & 15;
        u_s[c*20 + k] = u[j];
    }
    for (int j = t; j < NC; j += 256) dev_s[j] = 0.f;
    __syncthreads();
    for (int p = 0; p < ppb; ++p) {
        const int i = (b*ppb + p)*256 + t;
        const int seg = sam[i];
        if (seg > 0) {
            const int cl = seg - 1;
            const float4* sp = (const float4*)(semantic + (size_t)i*ND);
            const float4 a0 = sp[0], a1 = sp[1], a2 = sp[2], a3 = sp[3];
            const float4* up = (const float4*)(u_s + cl*20);
            const float4 u0 = up[0], u1 = up[1], u2 = up[2], u3 = up[3];
            float q, d2 = 0.f;
            q = a0.x-u0.x; d2 += q*q;  q = a0.y-u0.y; d2 += q*q;
            q = a0.z-u0.z; d2 += q*q;  q = a0.w-u0.w; d2 += q*q;
            q = a1.x-u1.x; d2 += q*q;  q = a1.y-u1.y; d2 += q*q;
            q = a1.z-u1.z; d2 += q*q;  q = a1.w-u1.w; d2 += q*q;
            q = a2.x-u2.x; d2 += q*q;  q = a2.y-u2.y; d2 += q*q;
            q = a2.z-u2.z; d2 += q*q;  q = a2.w-u2.w; d2 += q*q;
            q = a3.x-u3.x; d2 += q*q;  q = a3.y-u3.y; d2 += q*q;
            q = a3.z-u3.z; d2 += q*q;  q = a3.w-u3.w; d2 += q*q;
            atomicAdd(&dev_s[cl], sqrtf(d2));
        }
    }
    __syncthreads();
    for (int j = t; j < NC; j += 256) devpart[b*NC + j] = dev_s[j];
}

// ---------------- kP2: per-class phi -> uphi, validity bitmask ----------------
__global__ __launch_bounds__(256) void kP2(
    const float* __restrict__ devpart, const float* __restrict__ cnt,
    const float* __restrict__ u, float* __restrict__ uphi,
    unsigned* __restrict__ mask, int nblkC)
{
    const int c = blockIdx.x;
    const int t = threadIdx.x;

    float dv = (t < nblkC) ? devpart[t*NC + c] : 0.f;
#pragma unroll
    for (int off = 32; off > 0; off >>= 1) dv += __shfl_xor(dv, off);
    __shared__ float dred[4];
    __shared__ float inv_s;
    if ((t & 63) == 0) dred[t >> 6] = dv;
    __syncthreads();

    if (t == 0) {
        const float dtot = dred[0]+dred[1]+dred[2]+dred[3];
        const float cs = cnt[c];
        const float csafe = fmaxf(cs, 1.f);
        const float phiraw = dtot / (csafe * logf(cs + 10.f));
        const float phi = fminf(fmaxf(phiraw * 10.f, 0.1f), 1.f);
        inv_s = 1.f / phi;
        if (cs > 2.0f) atomicOr(&mask[c >> 5], 1u << (c & 31));
    }
    __syncthreads();
    if (t < 16) uphi[c*ND + t] = u[c*ND + t] * inv_s;
}

// ---------------- kD: NCE. u/phi via inline-asm s_load (SMEM pipe) ----------------
__global__ __launch_bounds__(256) void kD(
    const float* __restrict__ semantic, const int* __restrict__ sam,
    const float* __restrict__ uphi, const unsigned* __restrict__ maskbuf,
    float* __restrict__ scal, float* __restrict__ o_sem)
{
    __shared__ float part_d[4][128];
    __shared__ float red_s[4];
    const int t = threadIdx.x;
    const int lane = t & 63;
    const int w = __builtin_amdgcn_readfirstlane(t >> 6);

    const int base = blockIdx.x * 128;
    const float4* sp0 = (const float4*)(semantic + (size_t)(base + lane)*ND);
    const float4* sp1 = (const float4*)(semantic + (size_t)(base + 64 + lane)*ND);
    const float4 a00 = sp0[0], a01 = sp0[1], a02 = sp0[2], a03 = sp0[3];
    const float4 a10 = sp1[0], a11 = sp1[1], a12 = sp1[2], a13 = sp1[3];

    const unsigned long long msk = ((const unsigned long long*)maskbuf)[w];
    const float* upb = uphi + (w << 6) * ND;

    float denom0 = 0.f, denom1 = 0.f;
#pragma unroll 4
    for (int j = 0; j < 64; ++j) {
        f32x4v u0, u1, u2, u3;
        asm volatile(
            "s_load_dwordx4 %0, %4, 0x0\n\t"
            "s_load_dwordx4 %1, %4, 0x10\n\t"
            "s_load_dwordx4 %2, %4, 0x20\n\t"
            "s_load_dwordx4 %3, %4, 0x30\n\t"
            "s_waitcnt lgkmcnt(0)"
            : "=s"(u0), "=s"(u1), "=s"(u2), "=s"(u3)
            : "s"(upb + j*ND));
        const float mmf = ((msk >> j) & 1ull) ? 1.f : 0.f;
        const float d0 =
            a00.x*u0.x + a00.y*u0.y + a00.z*u0.z + a00.w*u0.w +
            a01.x*u1.x + a01.y*u1.y + a01.z*u1.z + a01.w*u1.w +
            a02.x*u2.x + a02.y*u2.y + a02.z*u2.z + a02.w*u2.w +
            a03.x*u3.x + a03.y*u3.y + a03.z*u3.z + a03.w*u3.w;
        const float d1 =
            a10.x*u0.x + a10.y*u0.y + a10.z*u0.z + a10.w*u0.w +
            a11.x*u1.x + a11.y*u1.y + a11.z*u1.z + a11.w*u1.w +
            a12.x*u2.x + a12.y*u2.y + a12.z*u2.z + a12.w*u2.w +
            a13.x*u3.x + a13.y*u3.y + a13.z*u3.z + a13.w*u3.w;
        denom0 += mmf * __expf(d0);
        denom1 += mmf * __expf(d1);
    }
    part_d[w][lane]      = denom0;
    part_d[w][64 + lane] = denom1;
    __syncthreads();

    float contrib = 0.f;
    if (t < 128) {
        const int seg = sam[base + t];
        const int cl = (seg > 0) ? (seg - 1) : 0;
        float4 b0 = a00, b1 = a01, b2 = a02, b3 = a03;
        if (w == 1) { b0 = a10; b1 = a11; b2 = a12; b3 = a13; }
        const float4* uo = (const float4*)(uphi + cl*ND);
        const float4 c0 = uo[0], c1 = uo[1], c2 = uo[2], c3 = uo[3];
        const float down =
            b0.x*c0.x + b0.y*c0.y + b0.z*c0.z + b0.w*c0.w +
            b1.x*c1.x + b1.y*c1.y + b1.z*c1.z + b1.w*c1.w +
            b2.x*c2.x + b2.y*c2.y + b2.z*c2.z + b2.w*c2.w +
            b3.x*c3.x + b3.y*c3.y + b3.z*c3.z + b3.w*c3.w;
        const unsigned mb = maskbuf[cl >> 5];
        const bool mv = (mb >> (cl & 31)) & 1u;
        const float dtot = part_d[0][t] + part_d[1][t] + part_d[2][t] + part_d[3][t] + 1e-6f;
        contrib = (seg > 0 && mv) ? (__logf(dtot) - down) : 0.f;
    }
#pragma unroll
    for (int off = 32; off > 0; off >>= 1) contrib += __shfl_xor(contrib, off);
    if ((t & 63) == 0) red_s[t >> 6] = contrib;
    __syncthreads();
    if (t == 0) atomicAdd(&scal[2], red_s[0]+red_s[1]+red_s[2]+red_s[3]);

    if (t == 0) {
        __threadfence();
        unsigned* done = (unsigned*)(scal + 3);
        const unsigned old = atomicAdd(done, 1u);
        if (old == gridDim.x - 1) {
            const float proto = atomicAdd(&scal[2], 0.f);
            const float nrm   = atomicAdd(&scal[0], 0.f);
            const float wsum  = atomicAdd(&scal[1], 0.f);
            o_sem[0] = 1e-4f * proto + 100.f * nrm / fmaxf(wsum, 1.f);
        }
    }
}

extern "C" void kernel_launch(void* const* d_in, const int* in_sizes, int n_in,
                              void* d_out, int out_size, void* d_ws, size_t ws_size,
                              hipStream_t stream)
{
    const float* rgb_pred = (const float*)d_in[0];
    const float* rgb_gt   = (const float*)d_in[1];
    const float* opacity  = (const float*)d_in[2];
    const float* wsv      = (const float*)d_in[3];
    const float* deltas   = (const float*)d_in[4];
    const float* tsv      = (const float*)d_in[5];
    const int*   rays_a   = (const int*)d_in[6];
    const int*   sam      = (const int*)d_in[7];
    const float* semantic = (const float*)d_in[8];

    float* out    = (float*)d_out;
    float* o_rgb  = out;                 // 196608
    float* o_opac = out + 196608;        // 65536
    float* o_dist = out + 262144;        // 65536
    float* o_sem  = out + 327680;        // 1
    float* wsf    = (float*)d_ws;

    int nblkA = 256, nblkC = 256;
    size_t need = ((size_t)nblkA*NC*(ND+1) + (size_t)nblkC*NC + NC + 2*NC*ND + 16) * 4;
    if (ws_size < need) { nblkA = 128; nblkC = 128; }
    const int ppbA = NPIX / (nblkA * 256);
    const int ppbC = NPIX / (nblkC * 256);

    float*    w_cntpart = wsf;
    float*    w_usum    = w_cntpart + (size_t)nblkA*NC;
    float*    w_devpart = w_usum + (size_t)nblkA*NC*ND;
    float*    w_cnt     = w_devpart + (size_t)nblkC*NC;
    float*    w_u       = w_cnt + NC;
    float*    w_uphi    = w_u + NC*ND;
    float*    w_scal    = w_uphi + NC*ND;   // [0]=norm [1]=wsum [2]=proto [3]=done
    unsigned* w_mask    = (unsigned*)(w_scal + 4);  // 8 dwords validity bitmask

    hipMemsetAsync(w_scal, 0, 12*sizeof(float), stream);

    kA<<<nblkA, 256, 0, stream>>>(rgb_pred, rgb_gt, opacity, sam, semantic,
                                  o_rgb, o_opac, w_cntpart, w_usum, w_scal, ppbA);
    kDist<<<NRAYS/RPB, RPB, 0, stream>>>(wsv, deltas, tsv, rays_a, o_dist);
    kP1<<<NC, 256, 0, stream>>>(w_cntpart, w_usum, w_cnt, w_u, nblkA);
    kC<<<nblkC, 256, 0, stream>>>(semantic, sam, w_u, w_devpart, ppbC);
    kP2<<<NC, 256, 0, stream>>>(w_devpart, w_cnt, w_u, w_uphi, w_mask, nblkC);
    kD<<<NPIX/128, 256, 0, stream>>>(semantic, sam, w_uphi, w_mask, w_scal, o_sem);
}

// Round 10
// 64.044 us; speedup vs baseline: 1.3862x; 1.3862x over previous
//
#include <hip/hip_runtime.h>
#include <hip/hip_bf16.h>

#define NPIX 65536
#define NRAYS 65536
#define SS 48
#define NC 256
#define ND 16
#define RPB 128   // rays per kDist block (128 threads)

typedef __attribute__((ext_vector_type(8))) short short8;
typedef __attribute__((ext_vector_type(4))) float f32x4;

__device__ __forceinline__ unsigned short f2bf(float x) {
    unsigned u = __float_as_uint(x);
    unsigned r = u + 0x7fff + ((u >> 16) & 1);
    return (unsigned short)(r >> 16);
}
__device__ __forceinline__ float bf2f(unsigned short h) {
    return __uint_as_float(((unsigned)h) << 16);
}

// ---------------- kA: pixel pass (rgb, opac, class count/sum, norm) ----------------
__global__ __launch_bounds__(256) void kA(
    const float* __restrict__ rgb_pred, const float* __restrict__ rgb_gt,
    const float* __restrict__ opacity, const int* __restrict__ sam,
    const float* __restrict__ semantic,
    float* __restrict__ o_rgb, float* __restrict__ o_opac,
    float* __restrict__ cntpart, float* __restrict__ usumpart,
    float* __restrict__ scal, int ppbA)
{
    __shared__ float cnt_s[NC];
    __shared__ float us_s[NC*17];
    __shared__ float red_s[8];
    const int t = threadIdx.x;
    const int b = blockIdx.x;
    for (int j = t; j < NC; j += 256) cnt_s[j] = 0.f;
    for (int j = t; j < NC*17; j += 256) us_s[j] = 0.f;
    __syncthreads();
    float nloc = 0.f, wloc = 0.f;
    for (int p = 0; p < ppbA; ++p) {
        const int i = (b*ppbA + p)*256 + t;
        const float pr0 = rgb_pred[3*i+0], pr1 = rgb_pred[3*i+1], pr2 = rgb_pred[3*i+2];
        const float g0 = rgb_gt[3*i+0],  g1 = rgb_gt[3*i+1],  g2 = rgb_gt[3*i+2];
        const float d0 = pr0-g0, d1 = pr1-g1, d2 = pr2-g2;
        o_rgb[3*i+0] = d0*d0; o_rgb[3*i+1] = d1*d1; o_rgb[3*i+2] = d2*d2;
        const float o = opacity[i] + 1e-10f;
        o_opac[i] = -0.001f * o * logf(o);
        const float4* sp = (const float4*)(semantic + (size_t)i*ND);
        const float4 a0 = sp[0], a1 = sp[1], a2 = sp[2], a3 = sp[3];
        const int seg = sam[i];
        if (seg > 0) {
            const int cl = seg - 1;
            const float ss =
                a0.x*a0.x + a0.y*a0.y + a0.z*a0.z + a0.w*a0.w +
                a1.x*a1.x + a1.y*a1.y + a1.z*a1.z + a1.w*a1.w +
                a2.x*a2.x + a2.y*a2.y + a2.z*a2.z + a2.w*a2.w +
                a3.x*a3.x + a3.y*a3.y + a3.z*a3.z + a3.w*a3.w;
            const float dn = sqrtf(ss) - 1.f;
            nloc += dn*dn; wloc += 1.f;
            atomicAdd(&cnt_s[cl], 1.f);
            float* up = us_s + cl*17;
            atomicAdd(up+0,  a0.x); atomicAdd(up+1,  a0.y);
            atomicAdd(up+2,  a0.z); atomicAdd(up+3,  a0.w);
            atomicAdd(up+4,  a1.x); atomicAdd(up+5,  a1.y);
            atomicAdd(up+6,  a1.z); atomicAdd(up+7,  a1.w);
            atomicAdd(up+8,  a2.x); atomicAdd(up+9,  a2.y);
            atomicAdd(up+10, a2.z); atomicAdd(up+11, a2.w);
            atomicAdd(up+12, a3.x); atomicAdd(up+13, a3.y);
            atomicAdd(up+14, a3.z); atomicAdd(up+15, a3.w);
        }
    }
    __syncthreads();
    for (int j = t; j < NC; j += 256) cntpart[b*NC + j] = cnt_s[j];
    for (int j = t; j < NC*ND; j += 256) {
        const int c = j >> 4, k = j & 15;
        usumpart[(size_t)b*NC*ND + j] = us_s[c*17 + k];
    }
    for (int off = 32; off > 0; off >>= 1) {
        nloc += __shfl_down(nloc, off);
        wloc += __shfl_down(wloc, off);
    }
    if ((t & 63) == 0) { red_s[t>>6] = nloc; red_s[4 + (t>>6)] = wloc; }
    __syncthreads();
    if (t == 0) {
        atomicAdd(&scal[0], red_s[0]+red_s[1]+red_s[2]+red_s[3]);
        atomicAdd(&scal[1], red_s[4]+red_s[5]+red_s[6]+red_s[7]);
    }
}

// ---------------- kDist: LDS-transposed serial scan, 1 thread/ray ----------------
__global__ __launch_bounds__(128) void kDist(
    const float* __restrict__ wsv, const float* __restrict__ deltas,
    const float* __restrict__ tsv, const int* __restrict__ rays_a,
    float* __restrict__ o_dist)
{
    __shared__ float wS[SS][RPB+1];
    __shared__ float tS[SS][RPB+1];
    __shared__ float dS[SS][RPB+1];
    __shared__ int bad;
    const int t = threadIdx.x;
    const int r0 = blockIdx.x * RPB;
    const int ray = r0 + t;
    if (t == 0) bad = 0;
    __syncthreads();
    const int start = rays_a[3*ray + 1];
    const int cnt   = rays_a[3*ray + 2];
    if (start != ray*SS || cnt != SS) atomicAdd(&bad, 1);
    __syncthreads();

    if (bad == 0) {
        const size_t gb = (size_t)r0 * SS;
        const float4* gw = (const float4*)(wsv + gb);
        const float4* gt = (const float4*)(tsv + gb);
        const float4* gd = (const float4*)(deltas + gb);
        for (int i = t; i < RPB*SS/4; i += 128) {
            const int e = i*4;
            const int rr = e / SS;
            const int jj = e % SS;
            const float4 a = gw[i], b = gt[i], c = gd[i];
            wS[jj+0][rr]=a.x; wS[jj+1][rr]=a.y; wS[jj+2][rr]=a.z; wS[jj+3][rr]=a.w;
            tS[jj+0][rr]=b.x; tS[jj+1][rr]=b.y; tS[jj+2][rr]=b.z; tS[jj+3][rr]=b.w;
            dS[jj+0][rr]=c.x; dS[jj+1][rr]=c.y; dS[jj+2][rr]=c.z; dS[jj+3][rr]=c.w;
        }
        __syncthreads();
        float W = 0.f, WT = 0.f, acc = 0.f;
        for (int j = 0; j < SS; ++j) {
            const float w_ = wS[j][t], t_ = tS[j][t], d_ = dS[j][t];
            acc += 2.f*w_*(t_*W - WT) + w_*w_*d_*(1.f/3.f);
            W += w_; WT += w_*t_;
        }
        o_dist[ray] = 0.001f * acc;
    } else {
        float W = 0.f, WT = 0.f, acc = 0.f;
        for (int j = 0; j < cnt; ++j) {
            const float w_ = wsv[start+j], t_ = tsv[start+j], d_ = deltas[start+j];
            acc += 2.f*w_*(t_*W - WT) + w_*w_*d_*(1.f/3.f);
            W += w_; WT += w_*t_;
        }
        o_dist[ray] = 0.001f * acc;
    }
}

// ---------------- kP1: per-class block reduce -> cnt, u ----------------
__global__ __launch_bounds__(256) void kP1(
    const float* __restrict__ cntpart, const float* __restrict__ usumpart,
    float* __restrict__ cnt, float* __restrict__ u, int nblkA)
{
    const int c = blockIdx.x;
    const int t = threadIdx.x;
    const int kk = t & 15;
    const int s  = t >> 4;

    float us = 0.f;
    for (int b = s; b < nblkA; b += 16)
        us += usumpart[(size_t)b*(NC*ND) + c*ND + kk];

    __shared__ float lds[16][17];
    lds[s][kk] = us;

    float cs = (t < nblkA) ? cntpart[t*NC + c] : 0.f;
#pragma unroll
    for (int off = 32; off > 0; off >>= 1) cs += __shfl_xor(cs, off);
    __shared__ float cred[4];
    if ((t & 63) == 0) cred[t >> 6] = cs;
    __syncthreads();

    if (t < 16) {
        const float ctot = cred[0]+cred[1]+cred[2]+cred[3];
        float tot = 0.f;
#pragma unroll
        for (int s2 = 0; s2 < 16; ++s2) tot += lds[s2][t];
        u[c*ND + t] = tot / fmaxf(ctot, 1.f);
        if (t == 0) cnt[c] = ctot;
    }
}

// ---------------- kC: per-class deviation partials ----------------
__global__ __launch_bounds__(256) void kC(
    const float* __restrict__ semantic, const int* __restrict__ sam,
    const float* __restrict__ u, float* __restrict__ devpart, int ppb)
{
    __shared__ float u_s[NC*20];
    __shared__ float dev_s[NC];
    const int t = threadIdx.x, b = blockIdx.x;
    for (int j = t; j < NC*ND; j += 256) {
        const int c = j >> 4, k = j & 15;
        u_s[c*20 + k] = u[j];
    }
    for (int j = t; j < NC; j += 256) dev_s[j] = 0.f;
    __syncthreads();
    for (int p = 0; p < ppb; ++p) {
        const int i = (b*ppb + p)*256 + t;
        const int seg = sam[i];
        if (seg > 0) {
            const int cl = seg - 1;
            const float4* sp = (const float4*)(semantic + (size_t)i*ND);
            const float4 a0 = sp[0], a1 = sp[1], a2 = sp[2], a3 = sp[3];
            const float4* up = (const float4*)(u_s + cl*20);
            const float4 u0 = up[0], u1 = up[1], u2 = up[2], u3 = up[3];
            float q, d2 = 0.f;
            q = a0.x-u0.x; d2 += q*q;  q = a0.y-u0.y; d2 += q*q;
            q = a0.z-u0.z; d2 += q*q;  q = a0.w-u0.w; d2 += q*q;
            q = a1.x-u1.x; d2 += q*q;  q = a1.y-u1.y; d2 += q*q;
            q = a1.z-u1.z; d2 += q*q;  q = a1.w-u1.w; d2 += q*q;
            q = a2.x-u2.x; d2 += q*q;  q = a2.y-u2.y; d2 += q*q;
            q = a2.z-u2.z; d2 += q*q;  q = a2.w-u2.w; d2 += q*q;
            q = a3.x-u3.x; d2 += q*q;  q = a3.y-u3.y; d2 += q*q;
            q = a3.z-u3.z; d2 += q*q;  q = a3.w-u3.w; d2 += q*q;
            atomicAdd(&dev_s[cl], sqrtf(d2));
        }
    }
    __syncthreads();
    for (int j = t; j < NC; j += 256) devpart[b*NC + j] = dev_s[j];
}

// ---------------- kP2: per-class phi -> uphi (f32 + bf16 hi/lo), mask float ----------------
__global__ __launch_bounds__(256) void kP2(
    const float* __restrict__ devpart, const float* __restrict__ cnt,
    const float* __restrict__ u, float* __restrict__ uphi,
    unsigned short* __restrict__ uphi_h, unsigned short* __restrict__ uphi_l,
    float* __restrict__ mf, int nblkC)
{
    const int c = blockIdx.x;
    const int t = threadIdx.x;

    float dv = (t < nblkC) ? devpart[t*NC + c] : 0.f;
#pragma unroll
    for (int off = 32; off > 0; off >>= 1) dv += __shfl_xor(dv, off);
    __shared__ float dred[4];
    __shared__ float inv_s;
    if ((t & 63) == 0) dred[t >> 6] = dv;
    __syncthreads();

    if (t == 0) {
        const float dtot = dred[0]+dred[1]+dred[2]+dred[3];
        const float cs = cnt[c];
        const float csafe = fmaxf(cs, 1.f);
        const float phiraw = dtot / (csafe * logf(cs + 10.f));
        const float phi = fminf(fmaxf(phiraw * 10.f, 0.1f), 1.f);
        inv_s = 1.f / phi;
        mf[c] = (cs > 2.0f) ? 1.f : 0.f;
    }
    __syncthreads();
    if (t < 16) {
        const float v = u[c*ND + t] * inv_s;
        uphi[c*ND + t] = v;
        const unsigned short h = f2bf(v);
        uphi_h[c*ND + t] = h;
        uphi_l[c*ND + t] = f2bf(v - bf2f(h));
    }
}

// ---------------- kD: NCE via MFMA (bf16 hi/lo split, K=32 packing) ----------------
// Block = 256 threads = 4 waves; wave handles 64 pixels x 256 classes.
// A = [sem_hi | sem_lo] (K=32), B1 = [u_hi | u_hi], B2 = [u_lo | 0]:
//   D = mfma(A,B2,0) then mfma(A,B1,D)  ->  hi*hi + lo*hi + hi*lo.
__global__ __launch_bounds__(256, 1) void kD(
    const float* __restrict__ semantic, const int* __restrict__ sam,
    const float* __restrict__ uphi,
    const unsigned short* __restrict__ uphi_h, const unsigned short* __restrict__ uphi_l,
    const float* __restrict__ mf,
    float* __restrict__ scal, float* __restrict__ o_sem)
{
    __shared__ float dlds[4][64];
    __shared__ float red_s[4];
    const int t = threadIdx.x;
    const int lane = t & 63;
    const int w = t >> 6;
    const int col = lane & 15;          // A-row / B-col / D-col
    const int g   = lane >> 4;          // k-octet group
    const int wbase = blockIdx.x * 256 + w * 64;

    // ---- A fragments: 4 pixel-tiles; lane holds dims (g&1)*8..+7 of pixel col,
    // hi-bf16 if g<2 else lo-bf16  (A = [hi | lo] along K=32)
    short8 A[4];
#pragma unroll
    for (int pt = 0; pt < 4; ++pt) {
        const float* sp = semantic + (size_t)(wbase + pt*16 + col)*ND + (g & 1)*8;
        const float4 f0 = ((const float4*)sp)[0];
        const float4 f1 = ((const float4*)sp)[1];
        float fv[8] = {f0.x,f0.y,f0.z,f0.w, f1.x,f1.y,f1.z,f1.w};
        short8 a;
#pragma unroll
        for (int i = 0; i < 8; ++i) {
            const unsigned short h = f2bf(fv[i]);
            const unsigned short l = f2bf(fv[i] - bf2f(h));
            a[i] = (short)((g < 2) ? h : l);
        }
        A[pt] = a;
    }

    // ---- B fragments: 16 class-tiles (precomputed hi/lo in ws)
    short8 B1[16], B2[16];
    const short8* Bh = (const short8*)uphi_h;
    const short8* Bl = (const short8*)uphi_l;
    const short8 zero8 = {0,0,0,0,0,0,0,0};
#pragma unroll
    for (int ct = 0; ct < 16; ++ct) {
        const int cls = ct*16 + col;
        const int idx = cls*2 + (g & 1);
        B1[ct] = Bh[idx];                       // [hi | hi]
        B2[ct] = (g < 2) ? Bl[idx] : zero8;     // [lo | 0]
    }

    // ---- per-lane mask floats for its 16 class columns
    float mfv[16];
#pragma unroll
    for (int ct = 0; ct < 16; ++ct) mfv[ct] = mf[ct*16 + col];

    // ---- MFMA + exp accumulation
    float dacc[4][4] = {};
#pragma unroll
    for (int ct = 0; ct < 16; ++ct) {
#pragma unroll
        for (int pt = 0; pt < 4; ++pt) {
            f32x4 d = {0.f, 0.f, 0.f, 0.f};
            d = __builtin_amdgcn_mfma_f32_16x16x32_bf16(A[pt], B2[ct], d, 0, 0, 0);
            d = __builtin_amdgcn_mfma_f32_16x16x32_bf16(A[pt], B1[ct], d, 0, 0, 0);
#pragma unroll
            for (int r = 0; r < 4; ++r)
                dacc[pt][r] += mfv[ct] * __expf(d[r]);
        }
    }

    // ---- reduce across the 16 cols (lanes sharing g): xor 1,2,4,8
#pragma unroll
    for (int pt = 0; pt < 4; ++pt)
#pragma unroll
        for (int r = 0; r < 4; ++r) {
            float v = dacc[pt][r];
            v += __shfl_xor(v, 1);
            v += __shfl_xor(v, 2);
            v += __shfl_xor(v, 4);
            v += __shfl_xor(v, 8);
            dacc[pt][r] = v;
        }

    // ---- write denoms to LDS (pixel p = pt*16 + 4*g + r), read back at p=lane
    if (col == 0) {
#pragma unroll
        for (int pt = 0; pt < 4; ++pt)
#pragma unroll
            for (int r = 0; r < 4; ++r)
                dlds[w][pt*16 + 4*g + r] = dacc[pt][r];
    }
    // same-wave DS ordering guarantees write->read; no barrier needed
    const float denom = dlds[w][lane] + 1e-6f;

    // ---- numerator (exact fp32) + contrib
    const int p = wbase + lane;
    const int seg = sam[p];
    const int cl = (seg > 0) ? (seg - 1) : 0;
    const float4* sp = (const float4*)(semantic + (size_t)p*ND);
    const float4 b0 = sp[0], b1 = sp[1], b2 = sp[2], b3 = sp[3];
    const float4* uo = (const float4*)(uphi + cl*ND);
    const float4 c0 = uo[0], c1 = uo[1], c2 = uo[2], c3 = uo[3];
    const float down =
        b0.x*c0.x + b0.y*c0.y + b0.z*c0.z + b0.w*c0.w +
        b1.x*c1.x + b1.y*c1.y + b1.z*c1.z + b1.w*c1.w +
        b2.x*c2.x + b2.y*c2.y + b2.z*c2.z + b2.w*c2.w +
        b3.x*c3.x + b3.y*c3.y + b3.z*c3.z + b3.w*c3.w;
    const float mo = mf[cl];
    float contrib = (seg > 0 && mo > 0.5f) ? (__logf(denom) - down) : 0.f;

#pragma unroll
    for (int off = 32; off > 0; off >>= 1) contrib += __shfl_xor(contrib, off);
    if ((t & 63) == 0) red_s[t >> 6] = contrib;
    __syncthreads();
    if (t == 0) atomicAdd(&scal[2], red_s[0]+red_s[1]+red_s[2]+red_s[3]);

    if (t == 0) {
        __threadfence();
        unsigned* done = (unsigned*)(scal + 3);
        const unsigned old = atomicAdd(done, 1u);
        if (old == gridDim.x - 1) {
            const float proto = atomicAdd(&scal[2], 0.f);
            const float nrm   = atomicAdd(&scal[0], 0.f);
            const float wsum  = atomicAdd(&scal[1], 0.f);
            o_sem[0] = 1e-4f * proto + 100.f * nrm / fmaxf(wsum, 1.f);
        }
    }
}

extern "C" void kernel_launch(void* const* d_in, const int* in_sizes, int n_in,
                              void* d_out, int out_size, void* d_ws, size_t ws_size,
                              hipStream_t stream)
{
    const float* rgb_pred = (const float*)d_in[0];
    const float* rgb_gt   = (const float*)d_in[1];
    const float* opacity  = (const float*)d_in[2];
    const float* wsv      = (const float*)d_in[3];
    const float* deltas   = (const float*)d_in[4];
    const float* tsv      = (const float*)d_in[5];
    const int*   rays_a   = (const int*)d_in[6];
    const int*   sam      = (const int*)d_in[7];
    const float* semantic = (const float*)d_in[8];

    float* out    = (float*)d_out;
    float* o_rgb  = out;                 // 196608
    float* o_opac = out + 196608;        // 65536
    float* o_dist = out + 262144;        // 65536
    float* o_sem  = out + 327680;        // 1
    float* wsf    = (float*)d_ws;

    int nblkA = 256, nblkC = 256;
    size_t need = ((size_t)nblkA*NC*(ND+1) + (size_t)nblkC*NC + NC + 2*NC*ND + NC*ND + 64) * 4;
    if (ws_size < need) { nblkA = 128; nblkC = 128; }
    const int ppbA = NPIX / (nblkA * 256);
    const int ppbC = NPIX / (nblkC * 256);

    float*          w_cntpart = wsf;
    float*          w_usum    = w_cntpart + (size_t)nblkA*NC;
    float*          w_devpart = w_usum + (size_t)nblkA*NC*ND;
    float*          w_cnt     = w_devpart + (size_t)nblkC*NC;
    float*          w_u       = w_cnt + NC;
    float*          w_uphi    = w_u + NC*ND;
    float*          w_scal    = w_uphi + NC*ND;          // [0]=norm [1]=wsum [2]=proto [3]=done
    float*          w_mf      = w_scal + 8;              // NC floats
    unsigned short* w_uh      = (unsigned short*)(w_mf + NC);        // NC*ND bf16 hi
    unsigned short* w_ul      = w_uh + NC*ND;                        // NC*ND bf16 lo

    hipMemsetAsync(w_scal, 0, 4*sizeof(float), stream);

    kA<<<nblkA, 256, 0, stream>>>(rgb_pred, rgb_gt, opacity, sam, semantic,
                                  o_rgb, o_opac, w_cntpart, w_usum, w_scal, ppbA);
    kDist<<<NRAYS/RPB, RPB, 0, stream>>>(wsv, deltas, tsv, rays_a, o_dist);
    kP1<<<NC, 256, 0, stream>>>(w_cntpart, w_usum, w_cnt, w_u, nblkA);
    kC<<<nblkC, 256, 0, stream>>>(semantic, sam, w_u, w_devpart, ppbC);
    kP2<<<NC, 256, 0, stream>>>(w_devpart, w_cnt, w_u, w_uphi, w_uh, w_ul, w_mf, nblkC);
    kD<<<NPIX/256, 256, 0, stream>>>(semantic, sam, w_uphi, w_uh, w_ul, w_mf, w_scal, o_sem);
}

// Round 11
// 54.390 us; speedup vs baseline: 1.6322x; 1.1775x over previous
//
#include <hip/hip_runtime.h>
#include <hip/hip_bf16.h>

#define NPIX 65536
#define NRAYS 65536
#define SS 48
#define NC 256
#define ND 16
#define RPB 128   // rays per kDist block (128 threads)

typedef __attribute__((ext_vector_type(8))) short short8;
typedef __attribute__((ext_vector_type(4))) float f32x4;

__device__ __forceinline__ unsigned short f2bf(float x) {
    unsigned u = __float_as_uint(x);
    unsigned r = u + 0x7fff + ((u >> 16) & 1);
    return (unsigned short)(r >> 16);
}
__device__ __forceinline__ float bf2f(unsigned short h) {
    return __uint_as_float(((unsigned)h) << 16);
}

// ---------------- kA: pixel pass (rgb, opac, class count/sum, norm partials) ----------------
__global__ __launch_bounds__(256) void kA(
    const float* __restrict__ rgb_pred, const float* __restrict__ rgb_gt,
    const float* __restrict__ opacity, const int* __restrict__ sam,
    const float* __restrict__ semantic,
    float* __restrict__ o_rgb, float* __restrict__ o_opac,
    float* __restrict__ cntpart, float* __restrict__ usumpart,
    float* __restrict__ normpart, float* __restrict__ wsumpart, int ppbA)
{
    __shared__ float cnt_s[NC];
    __shared__ float us_s[NC*17];
    __shared__ float red_s[8];
    const int t = threadIdx.x;
    const int b = blockIdx.x;
    for (int j = t; j < NC; j += 256) cnt_s[j] = 0.f;
    for (int j = t; j < NC*17; j += 256) us_s[j] = 0.f;
    __syncthreads();
    float nloc = 0.f, wloc = 0.f;
    for (int p = 0; p < ppbA; ++p) {
        const int i = (b*ppbA + p)*256 + t;
        const float pr0 = rgb_pred[3*i+0], pr1 = rgb_pred[3*i+1], pr2 = rgb_pred[3*i+2];
        const float g0 = rgb_gt[3*i+0],  g1 = rgb_gt[3*i+1],  g2 = rgb_gt[3*i+2];
        const float d0 = pr0-g0, d1 = pr1-g1, d2 = pr2-g2;
        o_rgb[3*i+0] = d0*d0; o_rgb[3*i+1] = d1*d1; o_rgb[3*i+2] = d2*d2;
        const float o = opacity[i] + 1e-10f;
        o_opac[i] = -0.001f * o * logf(o);
        const float4* sp = (const float4*)(semantic + (size_t)i*ND);
        const float4 a0 = sp[0], a1 = sp[1], a2 = sp[2], a3 = sp[3];
        const int seg = sam[i];
        if (seg > 0) {
            const int cl = seg - 1;
            const float ss =
                a0.x*a0.x + a0.y*a0.y + a0.z*a0.z + a0.w*a0.w +
                a1.x*a1.x + a1.y*a1.y + a1.z*a1.z + a1.w*a1.w +
                a2.x*a2.x + a2.y*a2.y + a2.z*a2.z + a2.w*a2.w +
                a3.x*a3.x + a3.y*a3.y + a3.z*a3.z + a3.w*a3.w;
            const float dn = sqrtf(ss) - 1.f;
            nloc += dn*dn; wloc += 1.f;
            atomicAdd(&cnt_s[cl], 1.f);
            float* up = us_s + cl*17;
            atomicAdd(up+0,  a0.x); atomicAdd(up+1,  a0.y);
            atomicAdd(up+2,  a0.z); atomicAdd(up+3,  a0.w);
            atomicAdd(up+4,  a1.x); atomicAdd(up+5,  a1.y);
            atomicAdd(up+6,  a1.z); atomicAdd(up+7,  a1.w);
            atomicAdd(up+8,  a2.x); atomicAdd(up+9,  a2.y);
            atomicAdd(up+10, a2.z); atomicAdd(up+11, a2.w);
            atomicAdd(up+12, a3.x); atomicAdd(up+13, a3.y);
            atomicAdd(up+14, a3.z); atomicAdd(up+15, a3.w);
        }
    }
    __syncthreads();
    for (int j = t; j < NC; j += 256) cntpart[b*NC + j] = cnt_s[j];
    for (int j = t; j < NC*ND; j += 256) {
        const int c = j >> 4, k = j & 15;
        usumpart[(size_t)b*NC*ND + j] = us_s[c*17 + k];
    }
    for (int off = 32; off > 0; off >>= 1) {
        nloc += __shfl_down(nloc, off);
        wloc += __shfl_down(wloc, off);
    }
    if ((t & 63) == 0) { red_s[t>>6] = nloc; red_s[4 + (t>>6)] = wloc; }
    __syncthreads();
    if (t == 0) {
        normpart[b] = red_s[0]+red_s[1]+red_s[2]+red_s[3];
        wsumpart[b] = red_s[4]+red_s[5]+red_s[6]+red_s[7];
    }
}

// ---------------- kDist: LDS-transposed serial scan, 1 thread/ray ----------------
__global__ __launch_bounds__(128) void kDist(
    const float* __restrict__ wsv, const float* __restrict__ deltas,
    const float* __restrict__ tsv, const int* __restrict__ rays_a,
    float* __restrict__ o_dist)
{
    __shared__ float wS[SS][RPB+1];
    __shared__ float tS[SS][RPB+1];
    __shared__ float dS[SS][RPB+1];
    __shared__ int bad;
    const int t = threadIdx.x;
    const int r0 = blockIdx.x * RPB;
    const int ray = r0 + t;
    if (t == 0) bad = 0;
    __syncthreads();
    const int start = rays_a[3*ray + 1];
    const int cnt   = rays_a[3*ray + 2];
    if (start != ray*SS || cnt != SS) atomicAdd(&bad, 1);
    __syncthreads();

    if (bad == 0) {
        const size_t gb = (size_t)r0 * SS;
        const float4* gw = (const float4*)(wsv + gb);
        const float4* gt = (const float4*)(tsv + gb);
        const float4* gd = (const float4*)(deltas + gb);
        for (int i = t; i < RPB*SS/4; i += 128) {
            const int e = i*4;
            const int rr = e / SS;
            const int jj = e % SS;
            const float4 a = gw[i], b = gt[i], c = gd[i];
            wS[jj+0][rr]=a.x; wS[jj+1][rr]=a.y; wS[jj+2][rr]=a.z; wS[jj+3][rr]=a.w;
            tS[jj+0][rr]=b.x; tS[jj+1][rr]=b.y; tS[jj+2][rr]=b.z; tS[jj+3][rr]=b.w;
            dS[jj+0][rr]=c.x; dS[jj+1][rr]=c.y; dS[jj+2][rr]=c.z; dS[jj+3][rr]=c.w;
        }
        __syncthreads();
        float W = 0.f, WT = 0.f, acc = 0.f;
        for (int j = 0; j < SS; ++j) {
            const float w_ = wS[j][t], t_ = tS[j][t], d_ = dS[j][t];
            acc += 2.f*w_*(t_*W - WT) + w_*w_*d_*(1.f/3.f);
            W += w_; WT += w_*t_;
        }
        o_dist[ray] = 0.001f * acc;
    } else {
        float W = 0.f, WT = 0.f, acc = 0.f;
        for (int j = 0; j < cnt; ++j) {
            const float w_ = wsv[start+j], t_ = tsv[start+j], d_ = deltas[start+j];
            acc += 2.f*w_*(t_*W - WT) + w_*w_*d_*(1.f/3.f);
            W += w_; WT += w_*t_;
        }
        o_dist[ray] = 0.001f * acc;
    }
}

// ---------------- kP1: per-class block reduce -> cnt, u; block 0 also norm/wsum ----------------
__global__ __launch_bounds__(256) void kP1(
    const float* __restrict__ cntpart, const float* __restrict__ usumpart,
    const float* __restrict__ normpart, const float* __restrict__ wsumpart,
    float* __restrict__ cnt, float* __restrict__ u,
    float* __restrict__ scal, int nblkA)
{
    const int c = blockIdx.x;
    const int t = threadIdx.x;
    const int kk = t & 15;
    const int s  = t >> 4;

    float us = 0.f;
    for (int b = s; b < nblkA; b += 16)
        us += usumpart[(size_t)b*(NC*ND) + c*ND + kk];

    __shared__ float lds[16][17];
    lds[s][kk] = us;

    float cs = (t < nblkA) ? cntpart[t*NC + c] : 0.f;
#pragma unroll
    for (int off = 32; off > 0; off >>= 1) cs += __shfl_xor(cs, off);
    __shared__ float cred[4];
    if ((t & 63) == 0) cred[t >> 6] = cs;
    __syncthreads();

    if (t < 16) {
        const float ctot = cred[0]+cred[1]+cred[2]+cred[3];
        float tot = 0.f;
#pragma unroll
        for (int s2 = 0; s2 < 16; ++s2) tot += lds[s2][t];
        u[c*ND + t] = tot / fmaxf(ctot, 1.f);
        if (t == 0) cnt[c] = ctot;
    }

    if (c == 0) {
        // reduce norm/wsum per-block partials -> scal[0], scal[1] (plain store)
        float n = (t < nblkA) ? normpart[t] : 0.f;
        float w2 = (t < nblkA) ? wsumpart[t] : 0.f;
#pragma unroll
        for (int off = 32; off > 0; off >>= 1) {
            n  += __shfl_xor(n, off);
            w2 += __shfl_xor(w2, off);
        }
        __shared__ float nr[4], wr[4];
        if ((t & 63) == 0) { nr[t >> 6] = n; wr[t >> 6] = w2; }
        __syncthreads();
        if (t == 0) {
            scal[0] = nr[0]+nr[1]+nr[2]+nr[3];
            scal[1] = wr[0]+wr[1]+wr[2]+wr[3];
        }
    }
}

// ---------------- kC: per-class deviation partials ----------------
__global__ __launch_bounds__(256) void kC(
    const float* __restrict__ semantic, const int* __restrict__ sam,
    const float* __restrict__ u, float* __restrict__ devpart, int ppb)
{
    __shared__ float u_s[NC*20];
    __shared__ float dev_s[NC];
    const int t = threadIdx.x, b = blockIdx.x;
    for (int j = t; j < NC*ND; j += 256) {
        const int c = j >> 4, k = j & 15;
        u_s[c*20 + k] = u[j];
    }
    for (int j = t; j < NC; j += 256) dev_s[j] = 0.f;
    __syncthreads();
    for (int p = 0; p < ppb; ++p) {
        const int i = (b*ppb + p)*256 + t;
        const int seg = sam[i];
        if (seg > 0) {
            const int cl = seg - 1;
            const float4* sp = (const float4*)(semantic + (size_t)i*ND);
            const float4 a0 = sp[0], a1 = sp[1], a2 = sp[2], a3 = sp[3];
            const float4* up = (const float4*)(u_s + cl*20);
            const float4 u0 = up[0], u1 = up[1], u2 = up[2], u3 = up[3];
            float q, d2 = 0.f;
            q = a0.x-u0.x; d2 += q*q;  q = a0.y-u0.y; d2 += q*q;
            q = a0.z-u0.z; d2 += q*q;  q = a0.w-u0.w; d2 += q*q;
            q = a1.x-u1.x; d2 += q*q;  q = a1.y-u1.y; d2 += q*q;
            q = a1.z-u1.z; d2 += q*q;  q = a1.w-u1.w; d2 += q*q;
            q = a2.x-u2.x; d2 += q*q;  q = a2.y-u2.y; d2 += q*q;
            q = a2.z-u2.z; d2 += q*q;  q = a2.w-u2.w; d2 += q*q;
            q = a3.x-u3.x; d2 += q*q;  q = a3.y-u3.y; d2 += q*q;
            q = a3.z-u3.z; d2 += q*q;  q = a3.w-u3.w; d2 += q*q;
            atomicAdd(&dev_s[cl], sqrtf(d2));
        }
    }
    __syncthreads();
    for (int j = t; j < NC; j += 256) devpart[b*NC + j] = dev_s[j];
}

// ---------------- kP2: per-class phi -> uphi (f32 + bf16 hi/lo), mask; zero scal[2]/done ----------------
__global__ __launch_bounds__(256) void kP2(
    const float* __restrict__ devpart, const float* __restrict__ cnt,
    const float* __restrict__ u, float* __restrict__ uphi,
    unsigned short* __restrict__ uphi_h, unsigned short* __restrict__ uphi_l,
    float* __restrict__ mf, float* __restrict__ scal, int nblkC)
{
    const int c = blockIdx.x;
    const int t = threadIdx.x;

    if (c == 0 && t == 0) {            // zero proto accumulator + done counter (pre-kD)
        scal[2] = 0.f;
        ((unsigned*)scal)[3] = 0u;
    }

    float dv = (t < nblkC) ? devpart[t*NC + c] : 0.f;
#pragma unroll
    for (int off = 32; off > 0; off >>= 1) dv += __shfl_xor(dv, off);
    __shared__ float dred[4];
    __shared__ float inv_s;
    if ((t & 63) == 0) dred[t >> 6] = dv;
    __syncthreads();

    if (t == 0) {
        const float dtot = dred[0]+dred[1]+dred[2]+dred[3];
        const float cs = cnt[c];
        const float csafe = fmaxf(cs, 1.f);
        const float phiraw = dtot / (csafe * logf(cs + 10.f));
        const float phi = fminf(fmaxf(phiraw * 10.f, 0.1f), 1.f);
        inv_s = 1.f / phi;
        mf[c] = (cs > 2.0f) ? 1.f : 0.f;
    }
    __syncthreads();
    if (t < 16) {
        const float v = u[c*ND + t] * inv_s;
        uphi[c*ND + t] = v;
        const unsigned short h = f2bf(v);
        uphi_h[c*ND + t] = h;
        uphi_l[c*ND + t] = f2bf(v - bf2f(h));
    }
}

// ---------------- kD: NCE via MFMA (bf16 hi/lo split, K=32 packing) ----------------
__global__ __launch_bounds__(256, 1) void kD(
    const float* __restrict__ semantic, const int* __restrict__ sam,
    const float* __restrict__ uphi,
    const unsigned short* __restrict__ uphi_h, const unsigned short* __restrict__ uphi_l,
    const float* __restrict__ mf,
    float* __restrict__ scal, float* __restrict__ o_sem)
{
    __shared__ float dlds[4][64];
    __shared__ float red_s[4];
    const int t = threadIdx.x;
    const int lane = t & 63;
    const int w = t >> 6;
    const int col = lane & 15;
    const int g   = lane >> 4;
    const int wbase = blockIdx.x * 256 + w * 64;

    short8 A[4];
#pragma unroll
    for (int pt = 0; pt < 4; ++pt) {
        const float* sp = semantic + (size_t)(wbase + pt*16 + col)*ND + (g & 1)*8;
        const float4 f0 = ((const float4*)sp)[0];
        const float4 f1 = ((const float4*)sp)[1];
        float fv[8] = {f0.x,f0.y,f0.z,f0.w, f1.x,f1.y,f1.z,f1.w};
        short8 a;
#pragma unroll
        for (int i = 0; i < 8; ++i) {
            const unsigned short h = f2bf(fv[i]);
            const unsigned short l = f2bf(fv[i] - bf2f(h));
            a[i] = (short)((g < 2) ? h : l);
        }
        A[pt] = a;
    }

    short8 B1[16], B2[16];
    const short8* Bh = (const short8*)uphi_h;
    const short8* Bl = (const short8*)uphi_l;
    const short8 zero8 = {0,0,0,0,0,0,0,0};
#pragma unroll
    for (int ct = 0; ct < 16; ++ct) {
        const int cls = ct*16 + col;
        const int idx = cls*2 + (g & 1);
        B1[ct] = Bh[idx];
        B2[ct] = (g < 2) ? Bl[idx] : zero8;
    }

    float mfv[16];
#pragma unroll
    for (int ct = 0; ct < 16; ++ct) mfv[ct] = mf[ct*16 + col];

    float dacc[4][4] = {};
#pragma unroll
    for (int ct = 0; ct < 16; ++ct) {
#pragma unroll
        for (int pt = 0; pt < 4; ++pt) {
            f32x4 d = {0.f, 0.f, 0.f, 0.f};
            d = __builtin_amdgcn_mfma_f32_16x16x32_bf16(A[pt], B2[ct], d, 0, 0, 0);
            d = __builtin_amdgcn_mfma_f32_16x16x32_bf16(A[pt], B1[ct], d, 0, 0, 0);
#pragma unroll
            for (int r = 0; r < 4; ++r)
                dacc[pt][r] += mfv[ct] * __expf(d[r]);
        }
    }

#pragma unroll
    for (int pt = 0; pt < 4; ++pt)
#pragma unroll
        for (int r = 0; r < 4; ++r) {
            float v = dacc[pt][r];
            v += __shfl_xor(v, 1);
            v += __shfl_xor(v, 2);
            v += __shfl_xor(v, 4);
            v += __shfl_xor(v, 8);
            dacc[pt][r] = v;
        }

    if (col == 0) {
#pragma unroll
        for (int pt = 0; pt < 4; ++pt)
#pragma unroll
            for (int r = 0; r < 4; ++r)
                dlds[w][pt*16 + 4*g + r] = dacc[pt][r];
    }
    const float denom = dlds[w][lane] + 1e-6f;

    const int p = wbase + lane;
    const int seg = sam[p];
    const int cl = (seg > 0) ? (seg - 1) : 0;
    const float4* sp = (const float4*)(semantic + (size_t)p*ND);
    const float4 b0 = sp[0], b1 = sp[1], b2 = sp[2], b3 = sp[3];
    const float4* uo = (const float4*)(uphi + cl*ND);
    const float4 c0 = uo[0], c1 = uo[1], c2 = uo[2], c3 = uo[3];
    const float down =
        b0.x*c0.x + b0.y*c0.y + b0.z*c0.z + b0.w*c0.w +
        b1.x*c1.x + b1.y*c1.y + b1.z*c1.z + b1.w*c1.w +
        b2.x*c2.x + b2.y*c2.y + b2.z*c2.z + b2.w*c2.w +
        b3.x*c3.x + b3.y*c3.y + b3.z*c3.z + b3.w*c3.w;
    const float mo = mf[cl];
    float contrib = (seg > 0 && mo > 0.5f) ? (__logf(denom) - down) : 0.f;

#pragma unroll
    for (int off = 32; off > 0; off >>= 1) contrib += __shfl_xor(contrib, off);
    if ((t & 63) == 0) red_s[t >> 6] = contrib;
    __syncthreads();
    if (t == 0) atomicAdd(&scal[2], red_s[0]+red_s[1]+red_s[2]+red_s[3]);

    if (t == 0) {
        __threadfence();
        unsigned* done = (unsigned*)(scal + 3);
        const unsigned old = atomicAdd(done, 1u);
        if (old == gridDim.x - 1) {
            const float proto = atomicAdd(&scal[2], 0.f);
            const float nrm   = scal[0];
            const float wsum  = scal[1];
            o_sem[0] = 1e-4f * proto + 100.f * nrm / fmaxf(wsum, 1.f);
        }
    }
}

extern "C" void kernel_launch(void* const* d_in, const int* in_sizes, int n_in,
                              void* d_out, int out_size, void* d_ws, size_t ws_size,
                              hipStream_t stream)
{
    const float* rgb_pred = (const float*)d_in[0];
    const float* rgb_gt   = (const float*)d_in[1];
    const float* opacity  = (const float*)d_in[2];
    const float* wsv      = (const float*)d_in[3];
    const float* deltas   = (const float*)d_in[4];
    const float* tsv      = (const float*)d_in[5];
    const int*   rays_a   = (const int*)d_in[6];
    const int*   sam      = (const int*)d_in[7];
    const float* semantic = (const float*)d_in[8];

    float* out    = (float*)d_out;
    float* o_rgb  = out;                 // 196608
    float* o_opac = out + 196608;        // 65536
    float* o_dist = out + 262144;        // 65536
    float* o_sem  = out + 327680;        // 1
    float* wsf    = (float*)d_ws;

    int nblkA = 256, nblkC = 256;
    size_t need = ((size_t)nblkA*NC*(ND+1) + (size_t)nblkC*NC + NC + 2*NC*ND + NC*ND + 2*nblkA + 64) * 4;
    if (ws_size < need) { nblkA = 128; nblkC = 128; }
    const int ppbA = NPIX / (nblkA * 256);
    const int ppbC = NPIX / (nblkC * 256);

    float*          w_cntpart  = wsf;
    float*          w_usum     = w_cntpart + (size_t)nblkA*NC;
    float*          w_devpart  = w_usum + (size_t)nblkA*NC*ND;
    float*          w_cnt      = w_devpart + (size_t)nblkC*NC;
    float*          w_u        = w_cnt + NC;
    float*          w_uphi     = w_u + NC*ND;
    float*          w_scal     = w_uphi + NC*ND;          // [0]=norm [1]=wsum [2]=proto [3]=done
    float*          w_mf       = w_scal + 8;              // NC floats
    float*          w_normpart = w_mf + NC;               // nblkA floats
    float*          w_wsumpart = w_normpart + nblkA;      // nblkA floats
    unsigned short* w_uh       = (unsigned short*)(w_wsumpart + nblkA);  // NC*ND bf16 hi
    unsigned short* w_ul       = w_uh + NC*ND;                           // NC*ND bf16 lo

    kA<<<nblkA, 256, 0, stream>>>(rgb_pred, rgb_gt, opacity, sam, semantic,
                                  o_rgb, o_opac, w_cntpart, w_usum,
                                  w_normpart, w_wsumpart, ppbA);
    kDist<<<NRAYS/RPB, RPB, 0, stream>>>(wsv, deltas, tsv, rays_a, o_dist);
    kP1<<<NC, 256, 0, stream>>>(w_cntpart, w_usum, w_normpart, w_wsumpart,
                                w_cnt, w_u, w_scal, nblkA);
    kC<<<nblkC, 256, 0, stream>>>(semantic, sam, w_u, w_devpart, ppbC);
    kP2<<<NC, 256, 0, stream>>>(w_devpart, w_cnt, w_u, w_uphi, w_uh, w_ul,
                                w_mf, w_scal, nblkC);
    kD<<<NPIX/256, 256, 0, stream>>>(semantic, sam, w_uphi, w_uh, w_ul, w_mf, w_scal, o_sem);
}